// Round 1
// baseline (170.154 us; speedup 1.0000x reference)
//
#include <hip/hip_runtime.h>
#include <math.h>

// Problem constants (also derived at runtime from in_sizes/out_size):
//   B,H,W,K = 8,512,512,8 ; P = 1,200,000 ; npix = B*H*W = 2,097,152
// Reference collapses: only the FIRST fragment slot matters.
//   out[pix] = (idx0 < 0) ? (1,1,1) : shaded[idx0]
// because alphas are binary -> transmittance is 0 after first valid frag,
// and the final jnp.where overrides with bg whenever slot-0 is a hole.

#define AMBIENT  0.3f
#define DIFFUSE  0.7f
#define SPECULAR 0.2f

__device__ __forceinline__ void shade_point(
    int i,
    const float* __restrict__ points,
    const float* __restrict__ features,
    const float* __restrict__ normals,
    const float* __restrict__ cam_centers,
    const int* __restrict__ cloud_idx,
    float lx, float ly, float lz,
    float& r, float& g, float& b)
{
    const float nx = normals[3*i+0];
    const float ny = normals[3*i+1];
    const float nz = normals[3*i+2];
    const float ndl = nx*lx + ny*ly + nz*lz;
    const float diffuse = fmaxf(ndl, 0.0f);

    const int c = cloud_idx[i];
    float vx = cam_centers[3*c+0] - points[3*i+0];
    float vy = cam_centers[3*c+1] - points[3*i+1];
    float vz = cam_centers[3*c+2] - points[3*i+2];
    float vn = fmaxf(sqrtf(vx*vx + vy*vy + vz*vz), 1e-12f);
    vx /= vn; vy /= vn; vz /= vn;

    float hx = lx + vx, hy = ly + vy, hz = lz + vz;
    float hn = fmaxf(sqrtf(hx*hx + hy*hy + hz*hz), 1e-12f);
    hx /= hn; hy /= hn; hz /= hn;

    float ndh = fmaxf(nx*hx + ny*hy + nz*hz, 0.0f);
    // ndh^32 via 5 squarings (exact-enough vs powf)
    float s = ndh * ndh;  // ^2
    s = s * s;            // ^4
    s = s * s;            // ^8
    s = s * s;            // ^16
    s = s * s;            // ^32
    const float spec = SPECULAR * s;
    const float kd = AMBIENT + DIFFUSE * diffuse;

    r = fminf(fmaxf(features[3*i+0] * kd + spec, 0.0f), 1.0f);
    g = fminf(fmaxf(features[3*i+1] * kd + spec, 0.0f), 1.0f);
    b = fminf(fmaxf(features[3*i+2] * kd + spec, 0.0f), 1.0f);
}

__global__ void shade_kernel(
    const float* __restrict__ points,
    const float* __restrict__ features,
    const float* __restrict__ normals,
    const float* __restrict__ cam_centers,
    const int* __restrict__ cloud_idx,
    const float* __restrict__ light_dir,
    float4* __restrict__ shaded,
    int P)
{
    const int p = blockIdx.x * blockDim.x + threadIdx.x;
    if (p >= P) return;

    float lx = light_dir[0], ly = light_dir[1], lz = light_dir[2];
    const float ln = fmaxf(sqrtf(lx*lx + ly*ly + lz*lz), 1e-12f);
    lx /= ln; ly /= ln; lz /= ln;

    float r, g, b;
    shade_point(p, points, features, normals, cam_centers, cloud_idx,
                lx, ly, lz, r, g, b);
    shaded[p] = make_float4(r, g, b, 0.0f);
}

__global__ void composite_kernel(
    const int* __restrict__ idx,
    const float4* __restrict__ shaded,
    float* __restrict__ out,
    int npix, int K)
{
    const int p = blockIdx.x * blockDim.x + threadIdx.x;
    if (p >= npix) return;
    const int i0 = idx[(long long)p * K];
    float r, g, b;
    if (i0 < 0) {
        r = 1.0f; g = 1.0f; b = 1.0f;
    } else {
        const float4 s = shaded[i0];
        r = s.x; g = s.y; b = s.z;
    }
    out[3*p+0] = r;
    out[3*p+1] = g;
    out[3*p+2] = b;
}

// Fallback if d_ws can't hold the padded shaded buffer: fuse shading into
// the per-pixel pass (re-shades referenced points on the fly).
__global__ void fused_kernel(
    const int* __restrict__ idx,
    const float* __restrict__ points,
    const float* __restrict__ features,
    const float* __restrict__ normals,
    const float* __restrict__ cam_centers,
    const int* __restrict__ cloud_idx,
    const float* __restrict__ light_dir,
    float* __restrict__ out,
    int npix, int K)
{
    const int p = blockIdx.x * blockDim.x + threadIdx.x;
    if (p >= npix) return;

    const int i0 = idx[(long long)p * K];
    float r = 1.0f, g = 1.0f, b = 1.0f;
    if (i0 >= 0) {
        float lx = light_dir[0], ly = light_dir[1], lz = light_dir[2];
        const float ln = fmaxf(sqrtf(lx*lx + ly*ly + lz*lz), 1e-12f);
        lx /= ln; ly /= ln; lz /= ln;
        shade_point(i0, points, features, normals, cam_centers, cloud_idx,
                    lx, ly, lz, r, g, b);
    }
    out[3*p+0] = r;
    out[3*p+1] = g;
    out[3*p+2] = b;
}

extern "C" void kernel_launch(void* const* d_in, const int* in_sizes, int n_in,
                              void* d_out, int out_size, void* d_ws, size_t ws_size,
                              hipStream_t stream)
{
    const int*   idx        = (const int*)  d_in[0];
    const float* points     = (const float*)d_in[1];
    const float* features   = (const float*)d_in[2];
    const float* normals    = (const float*)d_in[3];
    const float* cam        = (const float*)d_in[4];
    const int*   cloud_idx  = (const int*)  d_in[5];
    const float* light_dir  = (const float*)d_in[6];
    float*       out        = (float*)      d_out;

    const int P    = in_sizes[5];           // points per packed cloud total
    const int npix = out_size / 3;          // B*H*W
    const int K    = in_sizes[0] / npix;    // fragments per pixel

    const int BS = 256;

    if (ws_size >= (size_t)P * sizeof(float4)) {
        float4* shaded = (float4*)d_ws;
        shade_kernel<<<(P + BS - 1) / BS, BS, 0, stream>>>(
            points, features, normals, cam, cloud_idx, light_dir, shaded, P);
        composite_kernel<<<(npix + BS - 1) / BS, BS, 0, stream>>>(
            idx, shaded, out, npix, K);
    } else {
        fused_kernel<<<(npix + BS - 1) / BS, BS, 0, stream>>>(
            idx, points, features, normals, cam, cloud_idx, light_dir,
            out, npix, K);
    }
}